// Round 10
// baseline (341.458 us; speedup 1.0000x reference)
//
#include <hip/hip_runtime.h>
#include <hip/hip_bf16.h>

#define NN 50000
#define EE 1600000
#define AGG_WAVES 2048   // 512 blocks x 4 waves; 8 waves/SIMD at VGPR~20

__device__ __forceinline__ float bflo(unsigned u) { return __uint_as_float(u << 16); }
__device__ __forceinline__ float bfhi(unsigned u) { return __uint_as_float(u & 0xffff0000u); }

// ---------------- K1: h = elu(x) @ W (stored bf16-packed) ; a_src/a_dst ----------------
// R7 version: block 256 = 4 waves, 32 rows/block (best measured residual).
__global__ __launch_bounds__(256) void k_proj(
    const float* __restrict__ x, const float* __restrict__ W,
    const float* __restrict__ att_src, const float* __restrict__ att_dst,
    unsigned* __restrict__ h2u, float* __restrict__ a_src, float* __restrict__ a_dst) {
  __shared__ float Wl[128 * 64];   // [k][c] row-major, 32 KB; float2 view = col pairs
  __shared__ float xs[32 * 129];   // 32 rows, padded, 16.5 KB
  int tid = threadIdx.x;
  int row0 = blockIdx.x * 32;
  for (int i = tid; i < 128 * 64; i += 256) Wl[i] = W[i];
  for (int i = tid; i < 32 * 128; i += 256) {
    int r = i >> 7, k = i & 127;
    int row = row0 + r;
    float v = (row < NN) ? x[row * 128 + k] : 0.f;
    xs[r * 129 + k] = v > 0.f ? v : (__expf(v) - 1.f);   // ELU
  }
  __syncthreads();
  int w = tid >> 6, lane = tid & 63;
  int rs = lane >> 5, c = lane & 31;
  int rbase = w * 8 + rs * 4;                 // block-local rows rbase..rbase+3
  float a0[4] = {0, 0, 0, 0}, a1[4] = {0, 0, 0, 0};
  const float2* W2 = (const float2*)Wl;
#pragma unroll 4
  for (int k = 0; k < 128; ++k) {
    float2 wv = W2[k * 32 + c];
#pragma unroll
    for (int j = 0; j < 4; ++j) {
      float xv = xs[(rbase + j) * 129 + k];
      a0[j] += xv * wv.x;
      a1[j] += xv * wv.y;
    }
  }
  int hh = c >> 4;
  float2 av_s = ((const float2*)att_src)[c];  // cols 2c,2c+1 of flat [2][32]
  float2 av_d = ((const float2*)att_dst)[c];
#pragma unroll
  for (int j = 0; j < 4; ++j) {
    int row = row0 + rbase + j;
    bool ok = row < NN;
    if (ok) {
      unsigned lo = (unsigned)__bfloat16_as_ushort(__float2bfloat16(a0[j]));
      unsigned hi = (unsigned)__bfloat16_as_ushort(__float2bfloat16(a1[j]));
      h2u[row * 32 + c] = lo | (hi << 16);
    }
    float ps = a0[j] * av_s.x + a1[j] * av_s.y;
    float pd = a0[j] * av_d.x + a1[j] * av_d.y;
#pragma unroll
    for (int o = 1; o < 16; o <<= 1) {        // reduce 16 lanes of this head group
      ps += __shfl_xor(ps, o);
      pd += __shfl_xor(pd, o);
    }
    if (ok && (c & 15) == 0) { a_src[row * 2 + hh] = ps; a_dst[row * 2 + hh] = pd; }
  }
}

// ---------------- K2: build 8 linked sublists/node + per-edge softmax weights ----------------
// One lane per edge: gathers two 8 B attention entries (L2-resident 800 KB),
// computes both heads' exp once, writes a 16 B record (src, next, w0, w1).
__global__ __launch_bounds__(256) void k_build(
    const int* __restrict__ src, const int* __restrict__ dst,
    const float2* __restrict__ a_src2, const float2* __restrict__ a_dst2,
    int* __restrict__ head8, int4* __restrict__ edge4) {
  int e = blockIdx.x * 256 + threadIdx.x;
  int s = src[e], d = dst[e];
  float2 as = a_src2[s], ad = a_dst2[d];
  float l0 = as.x + ad.x; l0 = fmaxf(l0, 0.2f * l0);
  float l1 = as.y + ad.y; l1 = fmaxf(l1, 0.2f * l1);
  int old = atomicExch(&head8[d * 8 + (e & 7)], e);
  edge4[e] = make_int4(s, old, __float_as_int(__expf(l0)), __float_as_int(__expf(l1)));
}

// ---------------- K3: weighted aggregate, persistent waves ----------------
// 2048 persistent waves; wave g processes nodes g, g+2048, ... (~24 each, CLT
// balances total work to ±4%). Removes the block-retirement tail that capped
// occupancy at ~67% with one-shot blocks. Per node: half-wave chases 4 of 8
// chains (8 = measured optimum: 4->78.4, 8->70.1, 16->75.2 us).
__global__ __launch_bounds__(256) void k_agg(
    const unsigned* __restrict__ h2u, const float* __restrict__ a_src,
    const float* __restrict__ a_dst, const int* __restrict__ head8,
    const int4* __restrict__ edge4, const float* __restrict__ bias,
    float* __restrict__ out) {
  int waveId = blockIdx.x * 4 + (threadIdx.x >> 6);
  int lane = threadIdx.x & 63;
  int c2 = lane & 31;          // column pair: cols 2*c2, 2*c2+1
  int half = lane >> 5;
  int hh = c2 >> 4;
  float2 b = ((const float2*)bias)[c2];

  for (int n = waveId; n < NN; n += AGG_WAVES) {
    float denom = 0.f, acc0 = 0.f, acc1 = 0.f;
    if (half == 0) {           // self loop (PyG add_self_loops), counted once
      float l0 = a_src[n * 2 + hh] + a_dst[n * 2 + hh];
      l0 = fmaxf(l0, 0.2f * l0);
      float es = __expf(l0);
      unsigned hv = h2u[n * 32 + c2];
      denom = es; acc0 = es * bflo(hv); acc1 = es * bfhi(hv);
    }
    int e0 = head8[n * 8 + half * 4 + 0];
    int e1 = head8[n * 8 + half * 4 + 1];
    int e2 = head8[n * 8 + half * 4 + 2];
    int e3 = head8[n * 8 + half * 4 + 3];
    while (__any(max(max(e0, e1), max(e2, e3)) >= 0)) {
      int4 p0 = edge4[max(e0, 0)];
      int4 p1 = edge4[max(e1, 0)];
      int4 p2 = edge4[max(e2, 0)];
      int4 p3 = edge4[max(e3, 0)];
      unsigned h0 = h2u[p0.x * 32 + c2], h1 = h2u[p1.x * 32 + c2];
      unsigned h2 = h2u[p2.x * 32 + c2], h3 = h2u[p3.x * 32 + c2];
      float x0 = (e0 >= 0) ? __int_as_float(hh ? p0.w : p0.z) : 0.f;
      float x1 = (e1 >= 0) ? __int_as_float(hh ? p1.w : p1.z) : 0.f;
      float x2 = (e2 >= 0) ? __int_as_float(hh ? p2.w : p2.z) : 0.f;
      float x3 = (e3 >= 0) ? __int_as_float(hh ? p3.w : p3.z) : 0.f;
      denom += (x0 + x1) + (x2 + x3);
      acc0 += x0 * bflo(h0) + x1 * bflo(h1) + x2 * bflo(h2) + x3 * bflo(h3);
      acc1 += x0 * bfhi(h0) + x1 * bfhi(h1) + x2 * bfhi(h2) + x3 * bfhi(h3);
      e0 = (e0 >= 0) ? p0.y : -1;
      e1 = (e1 >= 0) ? p1.y : -1;
      e2 = (e2 >= 0) ? p2.y : -1;
      e3 = (e3 >= 0) ? p3.y : -1;
    }
    denom += __shfl_xor(denom, 32);
    acc0  += __shfl_xor(acc0, 32);
    acc1  += __shfl_xor(acc1, 32);
    if (half == 0) {
      float inv = 1.f / (denom + 1e-16f);
      ((float2*)out)[n * 32 + c2] = make_float2(acc0 * inv + b.x, acc1 * inv + b.y);
    }
  }
}

extern "C" void kernel_launch(void* const* d_in, const int* in_sizes, int n_in,
                              void* d_out, int out_size, void* d_ws, size_t ws_size,
                              hipStream_t stream) {
  const float* x       = (const float*)d_in[0];
  const float* W       = (const float*)d_in[1];
  const float* att_src = (const float*)d_in[2];
  const float* att_dst = (const float*)d_in[3];
  const float* bias    = (const float*)d_in[4];
  const int* edge_index = (const int*)d_in[5];
  const int* esrc = edge_index;        // edge_index[0, :]
  const int* edst = edge_index + EE;   // edge_index[1, :]

  // Workspace layout (a_src/a_dst are 100K floats = 400,000 B EACH):
  char* base = (char*)d_ws;
  unsigned* h2u  = (unsigned*)base;                      // [0     .. 6.4M)   h bf16x2
  float* a_src_b = (float*)(base + 6400000);             // [6.4M  .. 6.8M)
  float* a_dst_b = (float*)(base + 6800000);             // [6.8M  .. 7.2M)
  int*   head8   = (int*)(base + 7200000);               // [7.2M  .. 8.8M)  400K i32
  int4*  edge4   = (int4*)(base + 8800000);              // [8.8M  .. 34.4M) 1.6M int4

  hipMemsetAsync(head8, 0xFF, 400000 * sizeof(int), stream);   // -1 sentinels
  k_proj<<<(NN + 31) / 32, 256, 0, stream>>>(x, W, att_src, att_dst, h2u,
                                             a_src_b, a_dst_b);
  k_build<<<EE / 256, 256, 0, stream>>>(esrc, edst, (const float2*)a_src_b,
                                        (const float2*)a_dst_b, head8, edge4);
  k_agg<<<AGG_WAVES / 4, 256, 0, stream>>>(h2u, a_src_b, a_dst_b, head8, edge4,
                                           bias, (float*)d_out);
}

// Round 11
// 305.393 us; speedup vs baseline: 1.1181x; 1.1181x over previous
//
#include <hip/hip_runtime.h>
#include <hip/hip_bf16.h>

#define NN 50000
#define EE 1600000

__device__ __forceinline__ float bflo(unsigned u) { return __uint_as_float(u << 16); }
__device__ __forceinline__ float bfhi(unsigned u) { return __uint_as_float(u & 0xffff0000u); }

// ---------------- K1: h = elu(x) @ W (stored bf16-packed) ; a_src/a_dst ----------------
// R7 version: block 256 = 4 waves, 32 rows/block.
__global__ __launch_bounds__(256) void k_proj(
    const float* __restrict__ x, const float* __restrict__ W,
    const float* __restrict__ att_src, const float* __restrict__ att_dst,
    unsigned* __restrict__ h2u, float* __restrict__ a_src, float* __restrict__ a_dst) {
  __shared__ float Wl[128 * 64];   // [k][c] row-major, 32 KB; float2 view = col pairs
  __shared__ float xs[32 * 129];   // 32 rows, padded, 16.5 KB
  int tid = threadIdx.x;
  int row0 = blockIdx.x * 32;
  for (int i = tid; i < 128 * 64; i += 256) Wl[i] = W[i];
  for (int i = tid; i < 32 * 128; i += 256) {
    int r = i >> 7, k = i & 127;
    int row = row0 + r;
    float v = (row < NN) ? x[row * 128 + k] : 0.f;
    xs[r * 129 + k] = v > 0.f ? v : (__expf(v) - 1.f);   // ELU
  }
  __syncthreads();
  int w = tid >> 6, lane = tid & 63;
  int rs = lane >> 5, c = lane & 31;
  int rbase = w * 8 + rs * 4;                 // block-local rows rbase..rbase+3
  float a0[4] = {0, 0, 0, 0}, a1[4] = {0, 0, 0, 0};
  const float2* W2 = (const float2*)Wl;
#pragma unroll 4
  for (int k = 0; k < 128; ++k) {
    float2 wv = W2[k * 32 + c];
#pragma unroll
    for (int j = 0; j < 4; ++j) {
      float xv = xs[(rbase + j) * 129 + k];
      a0[j] += xv * wv.x;
      a1[j] += xv * wv.y;
    }
  }
  int hh = c >> 4;
  float2 av_s = ((const float2*)att_src)[c];  // cols 2c,2c+1 of flat [2][32]
  float2 av_d = ((const float2*)att_dst)[c];
#pragma unroll
  for (int j = 0; j < 4; ++j) {
    int row = row0 + rbase + j;
    bool ok = row < NN;
    if (ok) {
      unsigned lo = (unsigned)__bfloat16_as_ushort(__float2bfloat16(a0[j]));
      unsigned hi = (unsigned)__bfloat16_as_ushort(__float2bfloat16(a1[j]));
      h2u[row * 32 + c] = lo | (hi << 16);
    }
    float ps = a0[j] * av_s.x + a1[j] * av_s.y;
    float pd = a0[j] * av_d.x + a1[j] * av_d.y;
#pragma unroll
    for (int o = 1; o < 16; o <<= 1) {        // reduce 16 lanes of this head group
      ps += __shfl_xor(ps, o);
      pd += __shfl_xor(pd, o);
    }
    if (ok && (c & 15) == 0) { a_src[row * 2 + hh] = ps; a_dst[row * 2 + hh] = pd; }
  }
}

// ---------------- K2: build 8 BALANCED sublists/node + per-edge softmax weights ----------
// seq = per-node arrival number -> chain = seq&7 gives within-node chain lengths
// differing by <=1 (vs Poisson(4) with e&7). k_agg iterations drop ~7.5 -> ~4.4.
__global__ __launch_bounds__(256) void k_build(
    const int* __restrict__ src, const int* __restrict__ dst,
    const float2* __restrict__ a_src2, const float2* __restrict__ a_dst2,
    int* __restrict__ cnt, int* __restrict__ head8, int4* __restrict__ edge4) {
  int e = blockIdx.x * 256 + threadIdx.x;
  int s = src[e], d = dst[e];
  float2 as = a_src2[s], ad = a_dst2[d];
  float l0 = as.x + ad.x; l0 = fmaxf(l0, 0.2f * l0);
  float l1 = as.y + ad.y; l1 = fmaxf(l1, 0.2f * l1);
  int seq = atomicAdd(&cnt[d], 1);
  int old = atomicExch(&head8[d * 8 + (seq & 7)], e);
  edge4[e] = make_int4(s, old, __float_as_int(__expf(l0)), __float_as_int(__expf(l1)));
}

// ---------------- K3: weighted aggregate (R7 structure, 12.5K one-shot blocks) --------
// one wave per dst node; each half-wave chases 4 of the node's 8 balanced chains.
__global__ __launch_bounds__(256) void k_agg(
    const unsigned* __restrict__ h2u, const float* __restrict__ a_src,
    const float* __restrict__ a_dst, const int* __restrict__ head8,
    const int4* __restrict__ edge4, const float* __restrict__ bias,
    float* __restrict__ out) {
  int n = blockIdx.x * 4 + (threadIdx.x >> 6);
  int lane = threadIdx.x & 63;
  int c2 = lane & 31;          // column pair: cols 2*c2, 2*c2+1
  int half = lane >> 5;
  int hh = c2 >> 4;

  float denom = 0.f, acc0 = 0.f, acc1 = 0.f;
  if (half == 0) {             // self loop (PyG add_self_loops), counted once
    float l0 = a_src[n * 2 + hh] + a_dst[n * 2 + hh];
    l0 = fmaxf(l0, 0.2f * l0);
    float es = __expf(l0);
    unsigned hv = h2u[n * 32 + c2];
    denom = es; acc0 = es * bflo(hv); acc1 = es * bfhi(hv);
  }

  int e0 = head8[n * 8 + half * 4 + 0];
  int e1 = head8[n * 8 + half * 4 + 1];
  int e2 = head8[n * 8 + half * 4 + 2];
  int e3 = head8[n * 8 + half * 4 + 3];
  while (__any(max(max(e0, e1), max(e2, e3)) >= 0)) {
    int4 p0 = edge4[max(e0, 0)];
    int4 p1 = edge4[max(e1, 0)];
    int4 p2 = edge4[max(e2, 0)];
    int4 p3 = edge4[max(e3, 0)];
    unsigned h0 = h2u[p0.x * 32 + c2], h1 = h2u[p1.x * 32 + c2];
    unsigned h2 = h2u[p2.x * 32 + c2], h3 = h2u[p3.x * 32 + c2];
    float x0 = (e0 >= 0) ? __int_as_float(hh ? p0.w : p0.z) : 0.f;
    float x1 = (e1 >= 0) ? __int_as_float(hh ? p1.w : p1.z) : 0.f;
    float x2 = (e2 >= 0) ? __int_as_float(hh ? p2.w : p2.z) : 0.f;
    float x3 = (e3 >= 0) ? __int_as_float(hh ? p3.w : p3.z) : 0.f;
    denom += (x0 + x1) + (x2 + x3);
    acc0 += x0 * bflo(h0) + x1 * bflo(h1) + x2 * bflo(h2) + x3 * bflo(h3);
    acc1 += x0 * bfhi(h0) + x1 * bfhi(h1) + x2 * bfhi(h2) + x3 * bfhi(h3);
    e0 = (e0 >= 0) ? p0.y : -1;
    e1 = (e1 >= 0) ? p1.y : -1;
    e2 = (e2 >= 0) ? p2.y : -1;
    e3 = (e3 >= 0) ? p3.y : -1;
  }
  denom += __shfl_xor(denom, 32);
  acc0  += __shfl_xor(acc0, 32);
  acc1  += __shfl_xor(acc1, 32);
  if (half == 0) {
    float inv = 1.f / (denom + 1e-16f);
    float2 b = ((const float2*)bias)[c2];
    ((float2*)out)[n * 32 + c2] = make_float2(acc0 * inv + b.x, acc1 * inv + b.y);
  }
}

extern "C" void kernel_launch(void* const* d_in, const int* in_sizes, int n_in,
                              void* d_out, int out_size, void* d_ws, size_t ws_size,
                              hipStream_t stream) {
  const float* x       = (const float*)d_in[0];
  const float* W       = (const float*)d_in[1];
  const float* att_src = (const float*)d_in[2];
  const float* att_dst = (const float*)d_in[3];
  const float* bias    = (const float*)d_in[4];
  const int* edge_index = (const int*)d_in[5];
  const int* esrc = edge_index;        // edge_index[0, :]
  const int* edst = edge_index + EE;   // edge_index[1, :]

  // Workspace layout (a_src/a_dst are 100K floats = 400,000 B EACH):
  char* base = (char*)d_ws;
  unsigned* h2u  = (unsigned*)base;                      // [0     .. 6.4M)   h bf16x2
  float* a_src_b = (float*)(base + 6400000);             // [6.4M  .. 6.8M)
  float* a_dst_b = (float*)(base + 6800000);             // [6.8M  .. 7.2M)
  int*   cnt     = (int*)(base + 7200000);               // [7.2M  .. 7.4M)  50K i32
  int*   head8   = (int*)(base + 7400000);               // [7.4M  .. 9.0M)  400K i32
  int4*  edge4   = (int4*)(base + 9000000);              // [9.0M  .. 34.6M) 1.6M int4

  hipMemsetAsync(cnt, 0, 50000 * sizeof(int), stream);
  hipMemsetAsync(head8, 0xFF, 400000 * sizeof(int), stream);   // -1 sentinels
  k_proj<<<(NN + 31) / 32, 256, 0, stream>>>(x, W, att_src, att_dst, h2u,
                                             a_src_b, a_dst_b);
  k_build<<<EE / 256, 256, 0, stream>>>(esrc, edst, (const float2*)a_src_b,
                                        (const float2*)a_dst_b, cnt, head8, edge4);
  k_agg<<<NN / 4, 256, 0, stream>>>(h2u, a_src_b, a_dst_b, head8, edge4, bias,
                                    (float*)d_out);
}

// Round 12
// 248.308 us; speedup vs baseline: 1.3751x; 1.2299x over previous
//
#include <hip/hip_runtime.h>
#include <hip/hip_bf16.h>

#define NN 50000
#define EE 1600000

using short8 = __attribute__((ext_vector_type(8))) short;   // 8 bf16 (4 VGPRs)
using float4v = __attribute__((ext_vector_type(4))) float;  // MFMA accumulator

__device__ __forceinline__ float bflo(unsigned u) { return __uint_as_float(u << 16); }
__device__ __forceinline__ float bfhi(unsigned u) { return __uint_as_float(u & 0xffff0000u); }
__device__ __forceinline__ unsigned short f2bf(float v) {
  return __bfloat16_as_ushort(__float2bfloat16(v));
}

// ---------------- K0: a_src/a_dst via collapsed matvec + head8 init ----------------
// a_src[n,h] = sum_k elu(x[n,k]) * wa_s[k,h],  wa_s = W @ att_src^T (128x2), computed
// per block in LDS. One wave per node, full-wave shfl reduction. Also writes the
// -1 sentinels into head8 (replaces the memset dispatch).
__global__ __launch_bounds__(256) void k_pre(
    const float* __restrict__ x, const float* __restrict__ W,
    const float* __restrict__ att_src, const float* __restrict__ att_dst,
    float2* __restrict__ a_src2, float2* __restrict__ a_dst2,
    int* __restrict__ head8, int nblocks) {
  __shared__ float wa_s[128][2], wa_d[128][2];
  int tid = threadIdx.x;
  {
    int k = tid >> 1, hh = tid & 1;
    const float* wrow = W + k * 64 + hh * 32;
    const float* as = att_src + hh * 32;
    const float* ad = att_dst + hh * 32;
    float ss = 0.f, dd = 0.f;
#pragma unroll 8
    for (int c = 0; c < 32; ++c) { float wv = wrow[c]; ss += wv * as[c]; dd += wv * ad[c]; }
    wa_s[k][hh] = ss; wa_d[k][hh] = dd;
  }
  int gsize = nblocks * 256;
  for (int i = blockIdx.x * 256 + tid; i < NN * 8; i += gsize) head8[i] = -1;
  __syncthreads();
  int w = tid >> 6, lane = tid & 63;
  int nwaves = nblocks * 4;
  for (int n = blockIdx.x * 4 + w; n < NN; n += nwaves) {
    float x0 = x[n * 128 + lane], x1 = x[n * 128 + 64 + lane];
    x0 = x0 > 0.f ? x0 : __expf(x0) - 1.f;
    x1 = x1 > 0.f ? x1 : __expf(x1) - 1.f;
    float s0 = x0 * wa_s[lane][0] + x1 * wa_s[lane + 64][0];
    float s1 = x0 * wa_s[lane][1] + x1 * wa_s[lane + 64][1];
    float d0 = x0 * wa_d[lane][0] + x1 * wa_d[lane + 64][0];
    float d1 = x0 * wa_d[lane][1] + x1 * wa_d[lane + 64][1];
#pragma unroll
    for (int o = 32; o > 0; o >>= 1) {
      s0 += __shfl_xor(s0, o); s1 += __shfl_xor(s1, o);
      d0 += __shfl_xor(d0, o); d1 += __shfl_xor(d1, o);
    }
    if (lane == 0) { a_src2[n] = make_float2(s0, s1); a_dst2[n] = make_float2(d0, d1); }
  }
}

// ---------------- K1: h = elu(x) @ W via bf16 MFMA (stored bf16-packed) ----------------
// block 256 = 4 waves, 64 rows/block; wave w -> rows w*16..w*16+15, all 64 cols.
// A-frag: A[m=lane&15][k=quad*8+j]; B-frag: B[k=quad*8+j][n=lane&15] (Wt = W^T in LDS);
// C/D: col=lane&15, row=quad*4+reg. LDS rows padded to 136 bf16 (stride 272 B ->
// 2-way bank aliasing only, which is free).
__global__ __launch_bounds__(256) void k_projm(
    const float* __restrict__ x, const float* __restrict__ W,
    unsigned* __restrict__ h2u) {
  __shared__ unsigned short Wt[64 * 136];   // [n][k] bf16, padded
  __shared__ unsigned short xs[64 * 136];   // [r][k] bf16 (ELU applied), padded
  int tid = threadIdx.x;
  int row0 = blockIdx.x * 64;
  for (int i = tid; i < 8192; i += 256) {          // stage W^T
    int k = i >> 6, n = i & 63;
    Wt[n * 136 + k] = f2bf(W[i]);
  }
  for (int i = tid; i < 4096; i += 256) {          // stage x rows (ELU, bf16, packed)
    int r = i >> 6, k2 = (i & 63) * 2;
    int row = row0 + r;
    float v0 = 0.f, v1 = 0.f;
    if (row < NN) { float2 xv = *(const float2*)&x[row * 128 + k2]; v0 = xv.x; v1 = xv.y; }
    v0 = v0 > 0.f ? v0 : __expf(v0) - 1.f;
    v1 = v1 > 0.f ? v1 : __expf(v1) - 1.f;
    *(unsigned*)&xs[r * 136 + k2] = (unsigned)f2bf(v0) | ((unsigned)f2bf(v1) << 16);
  }
  __syncthreads();
  int w = tid >> 6, lane = tid & 63;
  int m = lane & 15, quad = lane >> 4;
  float4v acc[4] = {{0,0,0,0},{0,0,0,0},{0,0,0,0},{0,0,0,0}};
#pragma unroll
  for (int ks = 0; ks < 4; ++ks) {
    int koff = quad * 8 + ks * 32;
    short8 af = *(const short8*)&xs[(w * 16 + m) * 136 + koff];
#pragma unroll
    for (int nt = 0; nt < 4; ++nt) {
      short8 bf = *(const short8*)&Wt[(nt * 16 + m) * 136 + koff];
      acc[nt] = __builtin_amdgcn_mfma_f32_16x16x32_bf16(af, bf, acc[nt], 0, 0, 0);
    }
  }
#pragma unroll
  for (int nt = 0; nt < 4; ++nt) {
#pragma unroll
    for (int reg = 0; reg < 4; ++reg) {
      float v = acc[nt][reg];
      float vhi = __shfl_xor(v, 1);                // partner column (m odd)
      int row = row0 + w * 16 + quad * 4 + reg;
      if (!(m & 1) && row < NN) {
        h2u[row * 32 + nt * 8 + (m >> 1)] =
            (unsigned)f2bf(v) | ((unsigned)f2bf(vhi) << 16);
      }
    }
  }
}

// ---------------- K2: build 8 linked sublists/node + per-edge softmax weights ----------
// R7 version: one lane per edge; single random atomicExch (1.6 MB table, L2-hot);
// a-gathers are L2-resident; 16 B coalesced record (src, next, w0, w1).
__global__ __launch_bounds__(256) void k_build(
    const int* __restrict__ src, const int* __restrict__ dst,
    const float2* __restrict__ a_src2, const float2* __restrict__ a_dst2,
    int* __restrict__ head8, int4* __restrict__ edge4) {
  int e = blockIdx.x * 256 + threadIdx.x;
  int s = src[e], d = dst[e];
  float2 as = a_src2[s], ad = a_dst2[d];
  float l0 = as.x + ad.x; l0 = fmaxf(l0, 0.2f * l0);
  float l1 = as.y + ad.y; l1 = fmaxf(l1, 0.2f * l1);
  int old = atomicExch(&head8[d * 8 + (e & 7)], e);
  edge4[e] = make_int4(s, old, __float_as_int(__expf(l0)), __float_as_int(__expf(l1)));
}

// ---------------- K3: weighted aggregate (R7 structure; 8 = measured chain optimum) ----
__global__ __launch_bounds__(256) void k_agg(
    const unsigned* __restrict__ h2u, const float2* __restrict__ a_src2,
    const float2* __restrict__ a_dst2, const int4* __restrict__ head8v,
    const int4* __restrict__ edge4, const float* __restrict__ bias,
    float* __restrict__ out) {
  int n = blockIdx.x * 4 + (threadIdx.x >> 6);
  int lane = threadIdx.x & 63;
  int c2 = lane & 31;          // column pair: cols 2*c2, 2*c2+1
  int half = lane >> 5;
  int hh = c2 >> 4;

  float denom = 0.f, acc0 = 0.f, acc1 = 0.f;
  if (half == 0) {             // self loop (PyG add_self_loops), counted once
    float2 as = a_src2[n], ad = a_dst2[n];
    float l0 = (hh ? as.y + ad.y : as.x + ad.x);
    l0 = fmaxf(l0, 0.2f * l0);
    float es = __expf(l0);
    unsigned hv = h2u[n * 32 + c2];
    denom = es; acc0 = es * bflo(hv); acc1 = es * bfhi(hv);
  }

  int4 hd = head8v[n * 2 + half];    // 4 chain heads in one 16 B load
  int e0 = hd.x, e1 = hd.y, e2 = hd.z, e3 = hd.w;
  while (__any(max(max(e0, e1), max(e2, e3)) >= 0)) {
    int4 p0 = edge4[max(e0, 0)];
    int4 p1 = edge4[max(e1, 0)];
    int4 p2 = edge4[max(e2, 0)];
    int4 p3 = edge4[max(e3, 0)];
    unsigned h0 = h2u[p0.x * 32 + c2], h1 = h2u[p1.x * 32 + c2];
    unsigned h2 = h2u[p2.x * 32 + c2], h3 = h2u[p3.x * 32 + c2];
    float x0 = (e0 >= 0) ? __int_as_float(hh ? p0.w : p0.z) : 0.f;
    float x1 = (e1 >= 0) ? __int_as_float(hh ? p1.w : p1.z) : 0.f;
    float x2 = (e2 >= 0) ? __int_as_float(hh ? p2.w : p2.z) : 0.f;
    float x3 = (e3 >= 0) ? __int_as_float(hh ? p3.w : p3.z) : 0.f;
    denom += (x0 + x1) + (x2 + x3);
    acc0 += x0 * bflo(h0) + x1 * bflo(h1) + x2 * bflo(h2) + x3 * bflo(h3);
    acc1 += x0 * bfhi(h0) + x1 * bfhi(h1) + x2 * bfhi(h2) + x3 * bfhi(h3);
    e0 = (e0 >= 0) ? p0.y : -1;
    e1 = (e1 >= 0) ? p1.y : -1;
    e2 = (e2 >= 0) ? p2.y : -1;
    e3 = (e3 >= 0) ? p3.y : -1;
  }
  denom += __shfl_xor(denom, 32);
  acc0  += __shfl_xor(acc0, 32);
  acc1  += __shfl_xor(acc1, 32);
  if (half == 0) {
    float inv = 1.f / (denom + 1e-16f);
    float2 b = ((const float2*)bias)[c2];
    ((float2*)out)[n * 32 + c2] = make_float2(acc0 * inv + b.x, acc1 * inv + b.y);
  }
}

extern "C" void kernel_launch(void* const* d_in, const int* in_sizes, int n_in,
                              void* d_out, int out_size, void* d_ws, size_t ws_size,
                              hipStream_t stream) {
  const float* x       = (const float*)d_in[0];
  const float* W       = (const float*)d_in[1];
  const float* att_src = (const float*)d_in[2];
  const float* att_dst = (const float*)d_in[3];
  const float* bias    = (const float*)d_in[4];
  const int* edge_index = (const int*)d_in[5];
  const int* esrc = edge_index;        // edge_index[0, :]
  const int* edst = edge_index + EE;   // edge_index[1, :]

  // Workspace layout:
  char* base = (char*)d_ws;
  unsigned* h2u  = (unsigned*)base;                      // [0     .. 6.4M)   h bf16x2
  float2* a_src2 = (float2*)(base + 6400000);            // [6.4M  .. 6.8M)  50K float2
  float2* a_dst2 = (float2*)(base + 6800000);            // [6.8M  .. 7.2M)  50K float2
  int*    head8  = (int*)(base + 7200000);               // [7.2M  .. 8.8M)  400K i32
  int4*   edge4  = (int4*)(base + 8800000);              // [8.8M  .. 34.4M) 1.6M int4

  const int PRE_BLOCKS = 1024;
  k_pre<<<PRE_BLOCKS, 256, 0, stream>>>(x, W, att_src, att_dst, a_src2, a_dst2,
                                        head8, PRE_BLOCKS);
  k_projm<<<(NN + 63) / 64, 256, 0, stream>>>(x, W, h2u);
  k_build<<<EE / 256, 256, 0, stream>>>(esrc, edst, a_src2, a_dst2, head8, edge4);
  k_agg<<<NN / 4, 256, 0, stream>>>(h2u, a_src2, a_dst2, (const int4*)head8,
                                    edge4, bias, (float*)d_out);
}